// Round 16
// baseline (53.680 us; speedup 1.0000x reference)
//
#include <hip/hip_runtime.h>

#define NN    16384
#define CBN   64
#define SUBV  16
#define KCODE 16
#define DOUTN 1024
#define DEP   4

typedef short bf16x8 __attribute__((ext_vector_type(8)));
typedef float f32x16 __attribute__((ext_vector_type(16)));

static __device__ __forceinline__ unsigned short f2bf(float f) {
  unsigned int u = __float_as_uint(f);
  u += 0x7FFFu + ((u >> 16) & 1u);   // RNE; inputs are normal randn, no NaN/Inf
  return (unsigned short)(u >> 16);
}

// global -> LDS direct copy, 16B/lane. LDS dest wave-uniform (HW adds lane*16).
static __device__ __forceinline__ void gld16(const void* g, void* l) {
  __builtin_amdgcn_global_load_lds(
      (const __attribute__((address_space(1))) unsigned int*)g,
      (__attribute__((address_space(3))) unsigned int*)(uintptr_t)l, 16, 0, 0);
}

// ---------------- kernel 1: table convert/swizzle + encode (R13 verbatim) ---
// blocks [0,64): build Tswz (bf16, pre-swizzled 32 KiB images) — first, so
// they overlap encode. blocks [64, 64+2048): encode 8 rows (xs-staged;
// proven best vs direct-line in R15 A/B).
__global__ __launch_bounds__(256) void prep_k(
    const float* __restrict__ x, const int* __restrict__ split_idxs,
    const float* __restrict__ split_vals, const float* __restrict__ Tg,
    unsigned char* __restrict__ codes, unsigned int* __restrict__ Tswz) {
  const int t = threadIdx.x;

  if (blockIdx.x < 64) {
    const int img = blockIdx.x;                   // = g8*8 + ch
    const int g = img >> 3, ch = img & 7;
    unsigned int* dst = Tswz + (size_t)img * 8192; // 8192 u32 = 32 KiB image
    const int colq = t & 31, kp = (t >> 5) & 7;
    #pragma unroll
    for (int cl = 0; cl < 8; ++cl) {
      const float* g0 = Tg + ((size_t)((ch * 8 + cl) * KCODE + 2 * kp)) * DOUTN
                        + g * 128 + colq * 4;
      float4 r0 = *(const float4*)g0;             // k=2kp   (coalesced)
      float4 r1 = *(const float4*)(g0 + DOUTN);   // k=2kp+1
      unsigned int pk[4] = {
        f2bf(r0.x) | ((unsigned int)f2bf(r1.x) << 16),
        f2bf(r0.y) | ((unsigned int)f2bf(r1.y) << 16),
        f2bf(r0.z) | ((unsigned int)f2bf(r1.z) << 16),
        f2bf(r0.w) | ((unsigned int)f2bf(r1.w) << 16)};
      unsigned key = (unsigned)(colq & 7) << 2;   // XOR on u32-idx bits[4:2]
      #pragma unroll
      for (int j = 0; j < 4; ++j)
        dst[cl * 1024 + ((((unsigned)(colq * 4 + j)) * 8 + (unsigned)kp) ^ key)]
            = pk[j];
    }
    return;
  }

  // ---- encode (xs-staged, quad-granular XOR swizzle) ----
  __shared__ __align__(16) float xs[8][SUBV * CBN];
  __shared__ int   sidxT[DEP * CBN];               // [d][c]
  __shared__ float svalT[DEP * (KCODE / 2) * CBN]; // [d][e][c]
  if (t < DEP * CBN) {
    int d = t >> 6, c = t & 63;
    sidxT[t] = split_idxs[c * DEP + d];
  }
  for (int i = t; i < DEP * (KCODE / 2) * CBN; i += 256) {
    int c = i & 63, de = i >> 6, d = de >> 3, e = de & 7;
    svalT[i] = split_vals[(c * DEP + d) * (KCODE / 2) + e];
  }
  const int n0 = (blockIdx.x - 64) * 8;
  const float4* xg = (const float4*)(x + (size_t)n0 * DOUTN);
  #pragma unroll
  for (int i = 0; i < 8; ++i) {                    // 8 rows * 256 float4/row
    int li = t + i * 256;
    int r = li >> 8, cpos = li & 255;
    float4 v = xg[r * 256 + cpos];
    int c = cpos >> 2, q = cpos & 3;
    *(float4*)&xs[r][c * SUBV + ((q ^ (c & 3)) << 2)] = v;
  }
  __syncthreads();
  const int c = t & 63, rg = t >> 6;
  #pragma unroll
  for (int i = 0; i < 2; ++i) {
    int nl = rg * 2 + i;
    int e = 0;
    #pragma unroll
    for (int d = 0; d < DEP; ++d) {
      int si = sidxT[d * 64 + c];
      float xv = xs[nl][c * SUBV + (((si >> 2) ^ (c & 3)) << 2) + (si & 3)];
      float th = svalT[(d * 8 + e) * 64 + c];
      e = 2 * e + (xv > th ? 1 : 0);
    }
    codes[(size_t)(n0 + nl) * CBN + c] = (unsigned char)e;
  }
}

// ---------------- kernel 2: one-hot MFMA gather-accumulate ----------------
// grid (16 colgroups, 32 rowgroups of 512) = 512 blocks; 512 thr = 8 waves;
// LDS 64 KiB (4-chunk phases) -> TWO CO-RESIDENT blocks/CU (R14's mistake was
// 1 block/CU = serial rounds). Independent blocks desynchronize: one block's
// epilogue writes + phase-staging drain under the other's MFMA compute —
// attacks the ~10us exposed write tail, the last big reducible term.
// Per-wave compute = R13 verbatim (wave = 64 rows x 64 cols, rt=2 x ct=2,
// u64-shift A-build, one-ahead prefetch of codes + B-frags, bias-in-acc).
__global__ __launch_bounds__(512, 4) void maddness_mfma(
    const unsigned int* __restrict__ Tswz, const float* __restrict__ bias,
    const unsigned char* __restrict__ codes, float* __restrict__ out) {
  __shared__ __align__(16) unsigned int Tb[16384];   // 64 KiB: 4 chunk slots

  const int t = threadIdx.x;
  const int wid = t >> 6, lane = t & 63, lrow = lane & 31, h = lane >> 5;
  const int g16 = blockIdx.x, g8 = g16 >> 1, half = g16 & 1;
  const int n0 = blockIdx.y * 512;
  const char* img = (const char*)Tswz + (size_t)g8 * 8 * 32768;

  // stage 4 chunks (chbase..chbase+3) into slots 0..3: 64 segs of 1024 B,
  // wave stages 8. seg gs: slot = gs>>4, s16 = gs&15, cl = s16>>1, pc = s16&1.
  #define STAGE(CHBASE)                                                      \
    {                                                                        \
      _Pragma("unroll")                                                      \
      for (int i_ = 0; i_ < 8; ++i_) {                                       \
        int gs = wid * 8 + i_;                                               \
        int slot = gs >> 4, s16 = gs & 15, cl = s16 >> 1, pc = s16 & 1;      \
        gld16(img + ((CHBASE) + slot) * 32768 + cl * 4096 + half * 2048      \
                  + pc * 1024 + lane * 16,                                   \
              (char*)Tb + gs * 1024);                                        \
      }                                                                      \
    }

  STAGE(0);

  // bias folded into acc init (col is lane-constant)
  const float bv0 = bias[g16 * 64 + lrow];
  const float bv1 = bias[g16 * 64 + 32 + lrow];
  f32x16 acc[2][2];
  #pragma unroll
  for (int rt = 0; rt < 2; ++rt)
    #pragma unroll
    for (int e = 0; e < 16; ++e) { acc[rt][0][e] = bv0; acc[rt][1][e] = bv1; }

  const unsigned char* crow0 = codes + (size_t)(n0 + wid * 64 + lrow) * CBN;
  const unsigned char* crow1 = crow0 + 32 * CBN;
  const unsigned h2 = 2u * (unsigned)h, h2p = h2 + 1u;
  const unsigned rb0 = ((unsigned)lrow * 16 + (unsigned)h * 8)
                     ^ ((((unsigned)lrow >> 2) & 7u) << 3);
  const unsigned cl32 = (unsigned)lrow + 32u;
  const unsigned rb1 = (cl32 * 16 + (unsigned)h * 8)
                     ^ (((cl32 >> 2) & 7u) << 3);

  __syncthreads();                                  // phase-0 chunks staged

  #pragma unroll
  for (int p = 0; p < 2; ++p) {
    const int chbase = p * 4;
    // software pipeline heads for this phase
    const int sl0 = wid & 3;
    unsigned long long qA0 = *(const unsigned long long*)(crow0 + (chbase + sl0) * 8);
    unsigned long long qA1 = *(const unsigned long long*)(crow1 + (chbase + sl0) * 8);
    const unsigned short* tbc = (const unsigned short*)Tb + sl0 * 8192;
    bf16x8 bP0 = *(const bf16x8*)(tbc + rb0);
    bf16x8 bP1 = *(const bf16x8*)(tbc + rb1);

    #pragma unroll
    for (int i = 0; i < 4; ++i) {
      const int sln = (wid + i + 1) & 3;            // next chunk slot
      const unsigned short* tbn = (const unsigned short*)Tb + sln * 8192;
      const unsigned long long q0 = qA0, q1 = qA1;
      if (i < 3) {                                  // prefetch next codes
        qA0 = *(const unsigned long long*)(crow0 + (chbase + sln) * 8);
        qA1 = *(const unsigned long long*)(crow1 + (chbase + sln) * 8);
      }
      #pragma unroll
      for (int cl = 0; cl < 8; ++cl) {
        const bf16x8 b0 = bP0, b1 = bP1;
        if (!(i == 3 && cl == 7)) {                 // prefetch next B-frags
          const unsigned short* tnx = (cl == 7) ? tbn : (tbc + (cl + 1) * 1024);
          bP0 = *(const bf16x8*)(tnx + rb0);
          bP1 = *(const bf16x8*)(tnx + rb1);
        }
        #pragma unroll
        for (int rt = 0; rt < 2; ++rt) {
          const unsigned q32 =
              (unsigned)((rt ? q1 : q0) >> ((cl & 4) ? 32 : 0));
          const unsigned bpos = 8u * (unsigned)(cl & 3);
          const unsigned sh  = (q32 >> bpos) & 3u;        // c & 3
          const unsigned key = (q32 >> (bpos + 2)) & 3u;  // c >> 2
          const unsigned long long tt = 0x3F80ULL << (sh << 4);
          union { unsigned long long q[2]; bf16x8 v; } A;
          A.q[0] = (key == h2)  ? tt : 0ULL;
          A.q[1] = (key == h2p) ? tt : 0ULL;
          acc[rt][0] = __builtin_amdgcn_mfma_f32_32x32x16_bf16(A.v, b0, acc[rt][0], 0, 0, 0);
          acc[rt][1] = __builtin_amdgcn_mfma_f32_32x32x16_bf16(A.v, b1, acc[rt][1], 0, 0, 0);
        }
      }
      tbc = tbn;
    }

    if (p == 0) {
      __syncthreads();                              // all reads of phase-0 done
      STAGE(4);                                     // overwrite with chunks 4..7
      __syncthreads();                              // phase-1 staged (vmcnt drained)
    }
  }

  // single epilogue (bias already in acc):
  // D layout col=lane&31, row=(reg&3)+8*(reg>>2)+4*(lane>>5)
  #pragma unroll
  for (int ct = 0; ct < 2; ++ct) {
    const int col = g16 * 64 + ct * 32 + lrow;
    #pragma unroll
    for (int rt = 0; rt < 2; ++rt)
      #pragma unroll
      for (int r = 0; r < 16; ++r) {
        int row = n0 + wid * 64 + rt * 32 + (r & 3) + 8 * (r >> 2) + 4 * h;
        out[(size_t)row * DOUTN + col] = acc[rt][ct][r];
      }
  }
}

extern "C" void kernel_launch(void* const* d_in, const int* in_sizes, int n_in,
                              void* d_out, int out_size, void* d_ws, size_t ws_size,
                              hipStream_t stream) {
  const float* x    = (const float*)d_in[0];
  const int*   sidx = (const int*)d_in[1];
  const float* sval = (const float*)d_in[2];
  const float* Tg   = (const float*)d_in[3];
  const float* bias = (const float*)d_in[4];
  float* out = (float*)d_out;
  unsigned char* codes = (unsigned char*)d_ws;                       // 1 MiB
  unsigned int*  Tswz  = (unsigned int*)((char*)d_ws + (1 << 20));   // 2 MiB

  prep_k<<<64 + NN / 8, 256, 0, stream>>>(x, sidx, sval, Tg, codes, Tswz);
  maddness_mfma<<<dim3(16, 32), 512, 0, stream>>>(Tswz, bias, codes, out);
}

// Round 17
// 46.682 us; speedup vs baseline: 1.1499x; 1.1499x over previous
//
#include <hip/hip_runtime.h>

#define NN    16384
#define CBN   64
#define SUBV  16
#define KCODE 16
#define DOUTN 1024
#define DEP   4

typedef int   i32x4  __attribute__((ext_vector_type(4)));
typedef int   i32x16 __attribute__((ext_vector_type(16)));

// global -> LDS direct copy, 16B/lane. LDS dest wave-uniform (HW adds lane*16).
static __device__ __forceinline__ void gld16(const void* g, void* l) {
  __builtin_amdgcn_global_load_lds(
      (const __attribute__((address_space(1))) unsigned int*)g,
      (__attribute__((address_space(3))) unsigned int*)(uintptr_t)l, 16, 0, 0);
}

// ---------------- kernel 1: i8 table quantize + encode ----------------
// blocks [0,64): each handles 16 output columns. Pass 1: per-column absmax
// over all 1024 (c,k) entries (coalesced, LDS tree, no atomics) -> scale =
// max/127 to global, inv in LDS. Pass 2: quantize T to i8 with the COLUMN
// scale (shared by all 64 codebooks -> i32 MFMA accumulation stays exact
// w.r.t. one scale) into image img[g16][pair32][h2][col64][16B] — the exact
// linear LDS layout kernel 2 stages: B-reads become contiguous 512B/half-wave,
// NO swizzle anywhere.
// blocks [64, 64+2048): encode 8 rows -> codes[n][c] u8 (R13 verbatim).
__global__ __launch_bounds__(256) void prep_k(
    const float* __restrict__ x, const int* __restrict__ split_idxs,
    const float* __restrict__ split_vals, const float* __restrict__ Tg,
    unsigned char* __restrict__ codes, unsigned char* __restrict__ img,
    float* __restrict__ scales) {
  const int t = threadIdx.x;

  if (blockIdx.x < 64) {
    __shared__ float pm[16][17];
    __shared__ float invs[16];
    const int col0 = blockIdx.x * 16;
    const int j = t & 15, rg = t >> 4;             // 16 cols x 16 row-groups
    float m = 0.f;
    for (int r = rg; r < 1024; r += 16)            // coalesced 64B rows
      m = fmaxf(m, fabsf(Tg[(size_t)r * DOUTN + col0 + j]));
    pm[rg][j] = m;
    __syncthreads();
    if (t < 16) {
      float mm = 0.f;
      #pragma unroll
      for (int k = 0; k < 16; ++k) mm = fmaxf(mm, pm[k][t]);
      scales[col0 + t] = mm * (1.f / 127.f);
      invs[t] = 127.f / mm;
    }
    __syncthreads();
    // pass 2: unit u = (pair p, half h, col j); thread does 4 units.
    #pragma unroll
    for (int ii = 0; ii < 4; ++ii) {
      int u = t + ii * 256;
      int p = u >> 5, h = (u >> 4) & 1, jj = u & 15;
      int c = 2 * p + h;
      int col = col0 + jj;
      const float* src = Tg + (size_t)c * KCODE * DOUTN + col;
      const float inv = invs[jj];
      unsigned int pk[4];
      #pragma unroll
      for (int q = 0; q < 4; ++q) {
        unsigned int w = 0;
        #pragma unroll
        for (int b = 0; b < 4; ++b) {
          float v = src[(size_t)(q * 4 + b) * DOUTN];   // k-strided, L2/L3-hot
          float r = rintf(v * inv);
          r = fminf(127.f, fmaxf(-127.f, r));
          w |= ((unsigned int)((int)r & 255)) << (8 * b);
        }
        pk[q] = w;
      }
      unsigned int* dst = (unsigned int*)(img + ((size_t)(col >> 6)) * 65536
                                          + p * 2048 + h * 1024 + (col & 63) * 16);
      dst[0] = pk[0]; dst[1] = pk[1]; dst[2] = pk[2]; dst[3] = pk[3];
    }
    return;
  }

  // ---- encode (R13 verbatim: xs-staged, quad-granular XOR swizzle) ----
  __shared__ __align__(16) float xs[8][SUBV * CBN];
  __shared__ int   sidxT[DEP * CBN];               // [d][c]
  __shared__ float svalT[DEP * (KCODE / 2) * CBN]; // [d][e][c]
  if (t < DEP * CBN) {
    int d = t >> 6, c = t & 63;
    sidxT[t] = split_idxs[c * DEP + d];
  }
  for (int i = t; i < DEP * (KCODE / 2) * CBN; i += 256) {
    int c = i & 63, de = i >> 6, d = de >> 3, e = de & 7;
    svalT[i] = split_vals[(c * DEP + d) * (KCODE / 2) + e];
  }
  const int n0 = (blockIdx.x - 64) * 8;
  const float4* xg = (const float4*)(x + (size_t)n0 * DOUTN);
  #pragma unroll
  for (int i = 0; i < 8; ++i) {                    // 8 rows * 256 float4/row
    int li = t + i * 256;
    int r = li >> 8, cpos = li & 255;
    float4 v = xg[r * 256 + cpos];
    int c = cpos >> 2, q = cpos & 3;
    *(float4*)&xs[r][c * SUBV + ((q ^ (c & 3)) << 2)] = v;
  }
  __syncthreads();
  const int c = t & 63, rg2 = t >> 6;
  #pragma unroll
  for (int i = 0; i < 2; ++i) {
    int nl = rg2 * 2 + i;
    int e = 0;
    #pragma unroll
    for (int d = 0; d < DEP; ++d) {
      int si = sidxT[d * 64 + c];
      float xv = xs[nl][c * SUBV + (((si >> 2) ^ (c & 3)) << 2) + (si & 3)];
      float th = svalT[(d * 8 + e) * 64 + c];
      e = 2 * e + (xv > th ? 1 : 0);
    }
    codes[(size_t)(n0 + nl) * CBN + c] = (unsigned char)e;
  }
}

// ---------------- kernel 2: one-hot i8 MFMA gather-accumulate ----------------
// grid (16 colgroups, 16 rowgroups) = 256 blocks = 1/CU; 1024 thr = 16 waves.
// R13 shell (one-shot gld16 stage — now only 64 KiB, ONE barrier, free-run,
// wid-stagger, one-ahead code prefetch, single epilogue). v_mfma_i32_32x32x32_i8:
// K=32 = TWO codebooks/MFMA (pair p covers codebooks 2p [h=0] and 2p+1 [h=1];
// same lane-half labeling on A and B so the HW k-mapping cancels).
// MFMA count, LDS bytes, A-builds, staged image all HALVE vs bf16.
// i32 accumulation exact; epilogue out = scale[col]*acc + bias.
__global__ __launch_bounds__(1024, 4) void maddness_mfma(
    const unsigned char* __restrict__ img, const float* __restrict__ scales,
    const float* __restrict__ bias, const unsigned char* __restrict__ codes,
    float* __restrict__ out) {
  __shared__ __align__(16) unsigned int Tb[16384];   // 64 KiB: [pair32][h2][col64][16B]

  const int t = threadIdx.x;
  const int wid = t >> 6, lane = t & 63, lrow = lane & 31, h = lane >> 5;
  const int g16 = blockIdx.x;
  const int n0 = blockIdx.y * 1024;
  const unsigned char* img_g = img + (size_t)g16 * 65536;

  // stage 64 KiB linearly: 64 segs of 1024 B; wave stages 4 (image == LDS layout)
  #pragma unroll
  for (int i = 0; i < 4; ++i) {
    int gs = wid * 4 + i;
    gld16(img_g + gs * 1024 + lane * 16, (char*)Tb + gs * 1024);
  }

  i32x16 acc[2][2];
  #pragma unroll
  for (int rt = 0; rt < 2; ++rt)
    #pragma unroll
    for (int ct = 0; ct < 2; ++ct)
      #pragma unroll
      for (int e = 0; e < 16; ++e) acc[rt][ct][e] = 0;

  const unsigned char* crow0 = codes + (size_t)(n0 + wid * 64 + lrow) * CBN;
  const unsigned char* crow1 = crow0 + 32 * CBN;
  const char* tb = (const char*)Tb;

  __syncthreads();                                  // the ONLY barrier

  // software pipeline head: codes for g=0
  const int gg0 = wid & 7;
  unsigned long long qA0 = *(const unsigned long long*)(crow0 + gg0 * 8);
  unsigned long long qA1 = *(const unsigned long long*)(crow1 + gg0 * 8);

  #pragma unroll
  for (int g = 0; g < 8; ++g) {                     // 8 u64 code groups
    const int gcur = (wid + g) & 7;
    const unsigned long long q0 = qA0, q1 = qA1;
    if (g < 7) {                                    // prefetch next codes
      const int ggn = (wid + g + 1) & 7;
      qA0 = *(const unsigned long long*)(crow0 + ggn * 8);
      qA1 = *(const unsigned long long*)(crow1 + ggn * 8);
    }
    #pragma unroll
    for (int pp = 0; pp < 4; ++pp) {                // 4 pairs per group
      const int p = gcur * 4 + pp;                  // codebooks 2p (h=0), 2p+1 (h=1)
      const char* pb = tb + p * 2048 + h * 1024 + lrow * 16;
      const i32x4 b0 = *(const i32x4*)pb;           // cols  0..31  (linear, no conflicts)
      const i32x4 b1 = *(const i32x4*)(pb + 512);   // cols 32..63
      const unsigned sh = (unsigned)((pp * 2 + h) * 8);
      #pragma unroll
      for (int rt = 0; rt < 2; ++rt) {
        const unsigned c4 = (unsigned)((rt ? q1 : q0) >> sh) & 15u;
        const unsigned long long tt = 1ULL << ((c4 & 7u) * 8u);
        union { unsigned long long q[2]; i32x4 v; } A;
        A.q[0] = (c4 < 8u) ? tt : 0ULL;             // one-hot byte = code of cb 2p+h
        A.q[1] = (c4 < 8u) ? 0ULL : tt;
        acc[rt][0] = __builtin_amdgcn_mfma_i32_32x32x32_i8(A.v, b0, acc[rt][0], 0, 0, 0);
        acc[rt][1] = __builtin_amdgcn_mfma_i32_32x32x32_i8(A.v, b1, acc[rt][1], 0, 0, 0);
      }
    }
  }

  // single epilogue: out = scale[col]*acc + bias[col]
  // D layout col=lane&31, row=(reg&3)+8*(reg>>2)+4*(lane>>5)
  #pragma unroll
  for (int ct = 0; ct < 2; ++ct) {
    const int col = g16 * 64 + ct * 32 + lrow;
    const float sc = scales[col];
    const float bv = bias[col];
    #pragma unroll
    for (int rt = 0; rt < 2; ++rt)
      #pragma unroll
      for (int r = 0; r < 16; ++r) {
        int row = n0 + wid * 64 + rt * 32 + (r & 3) + 8 * (r >> 2) + 4 * h;
        out[(size_t)row * DOUTN + col] = fmaf((float)acc[rt][ct][r], sc, bv);
      }
  }
}

extern "C" void kernel_launch(void* const* d_in, const int* in_sizes, int n_in,
                              void* d_out, int out_size, void* d_ws, size_t ws_size,
                              hipStream_t stream) {
  const float* x    = (const float*)d_in[0];
  const int*   sidx = (const int*)d_in[1];
  const float* sval = (const float*)d_in[2];
  const float* Tg   = (const float*)d_in[3];
  const float* bias = (const float*)d_in[4];
  float* out = (float*)d_out;
  unsigned char* codes  = (unsigned char*)d_ws;                      // 1 MiB
  unsigned char* img    = (unsigned char*)d_ws + (1 << 20);          // 1 MiB
  float*         scales = (float*)((char*)d_ws + (2 << 20));         // 4 KiB

  prep_k<<<64 + NN / 8, 256, 0, stream>>>(x, sidx, sval, Tg, codes, img, scales);
  maddness_mfma<<<dim3(16, 16), 1024, 0, stream>>>(img, scales, bias, codes, out);
}

// Round 18
// 46.672 us; speedup vs baseline: 1.1502x; 1.0002x over previous
//
#include <hip/hip_runtime.h>

#define NN    16384
#define CBN   64
#define SUBV  16
#define KCODE 16
#define DOUTN 1024
#define DEP   4

typedef int   i32x4  __attribute__((ext_vector_type(4)));
typedef int   i32x16 __attribute__((ext_vector_type(16)));

// global -> LDS direct copy, 16B/lane. LDS dest wave-uniform (HW adds lane*16).
static __device__ __forceinline__ void gld16(const void* g, void* l) {
  __builtin_amdgcn_global_load_lds(
      (const __attribute__((address_space(1))) unsigned int*)g,
      (__attribute__((address_space(3))) unsigned int*)(uintptr_t)l, 16, 0, 0);
}

// ---------------- kernel 1: i8 table quantize + encode (R17 verbatim) -------
__global__ __launch_bounds__(256) void prep_k(
    const float* __restrict__ x, const int* __restrict__ split_idxs,
    const float* __restrict__ split_vals, const float* __restrict__ Tg,
    unsigned char* __restrict__ codes, unsigned char* __restrict__ img,
    float* __restrict__ scales) {
  const int t = threadIdx.x;

  if (blockIdx.x < 64) {
    __shared__ float pm[16][17];
    __shared__ float invs[16];
    const int col0 = blockIdx.x * 16;
    const int j = t & 15, rg = t >> 4;             // 16 cols x 16 row-groups
    float m = 0.f;
    for (int r = rg; r < 1024; r += 16)            // coalesced 64B rows
      m = fmaxf(m, fabsf(Tg[(size_t)r * DOUTN + col0 + j]));
    pm[rg][j] = m;
    __syncthreads();
    if (t < 16) {
      float mm = 0.f;
      #pragma unroll
      for (int k = 0; k < 16; ++k) mm = fmaxf(mm, pm[k][t]);
      scales[col0 + t] = mm * (1.f / 127.f);
      invs[t] = 127.f / mm;
    }
    __syncthreads();
    // pass 2: unit u = (pair p, half h, col j); thread does 4 units.
    #pragma unroll
    for (int ii = 0; ii < 4; ++ii) {
      int u = t + ii * 256;
      int p = u >> 5, h = (u >> 4) & 1, jj = u & 15;
      int c = 2 * p + h;
      int col = col0 + jj;
      const float* src = Tg + (size_t)c * KCODE * DOUTN + col;
      const float inv = invs[jj];
      unsigned int pk[4];
      #pragma unroll
      for (int q = 0; q < 4; ++q) {
        unsigned int w = 0;
        #pragma unroll
        for (int b = 0; b < 4; ++b) {
          float v = src[(size_t)(q * 4 + b) * DOUTN];   // k-strided, L2/L3-hot
          float r = rintf(v * inv);
          r = fminf(127.f, fmaxf(-127.f, r));
          w |= ((unsigned int)((int)r & 255)) << (8 * b);
        }
        pk[q] = w;
      }
      unsigned int* dst = (unsigned int*)(img + ((size_t)(col >> 6)) * 65536
                                          + p * 2048 + h * 1024 + (col & 63) * 16);
      dst[0] = pk[0]; dst[1] = pk[1]; dst[2] = pk[2]; dst[3] = pk[3];
    }
    return;
  }

  // ---- encode (R13 verbatim: xs-staged, quad-granular XOR swizzle) ----
  __shared__ __align__(16) float xs[8][SUBV * CBN];
  __shared__ int   sidxT[DEP * CBN];               // [d][c]
  __shared__ float svalT[DEP * (KCODE / 2) * CBN]; // [d][e][c]
  if (t < DEP * CBN) {
    int d = t >> 6, c = t & 63;
    sidxT[t] = split_idxs[c * DEP + d];
  }
  for (int i = t; i < DEP * (KCODE / 2) * CBN; i += 256) {
    int c = i & 63, de = i >> 6, d = de >> 3, e = de & 7;
    svalT[i] = split_vals[(c * DEP + d) * (KCODE / 2) + e];
  }
  const int n0 = (blockIdx.x - 64) * 8;
  const float4* xg = (const float4*)(x + (size_t)n0 * DOUTN);
  #pragma unroll
  for (int i = 0; i < 8; ++i) {                    // 8 rows * 256 float4/row
    int li = t + i * 256;
    int r = li >> 8, cpos = li & 255;
    float4 v = xg[r * 256 + cpos];
    int c = cpos >> 2, q = cpos & 3;
    *(float4*)&xs[r][c * SUBV + ((q ^ (c & 3)) << 2)] = v;
  }
  __syncthreads();
  const int c = t & 63, rg2 = t >> 6;
  #pragma unroll
  for (int i = 0; i < 2; ++i) {
    int nl = rg2 * 2 + i;
    int e = 0;
    #pragma unroll
    for (int d = 0; d < DEP; ++d) {
      int si = sidxT[d * 64 + c];
      float xv = xs[nl][c * SUBV + (((si >> 2) ^ (c & 3)) << 2) + (si & 3)];
      float th = svalT[(d * 8 + e) * 64 + c];
      e = 2 * e + (xv > th ? 1 : 0);
    }
    codes[(size_t)(n0 + nl) * CBN + c] = (unsigned char)e;
  }
}

// ---------------- kernel 2: one-hot i8 MFMA, row-phase-split writes ---------
// grid (16 colgroups, 16 rowgroups) = 256 blocks = 1/CU; 1024 thr = 16 waves.
// R17 shell (64 KiB linear gld16 stage, ONE barrier, free-run, wid-stagger,
// one-ahead code prefetch, i8 K=32 = 2 codebooks/MFMA, exact i32 accum,
// out = scale[col]*acc + bias). NEW: the wave's two independent 32-row tiles
// are computed in two sequential PHASES, each writing immediately — phase A's
// 32 MiB chip-wide write burst drains under phase B's ~8.5us compute, halving
// the exposed write tail (was ~10.6us, the largest term). LDS B-reads double
// (2.6->5.2us, still under the 7.8us MFMA pipe); acc VGPRs halve.
__global__ __launch_bounds__(1024, 4) void maddness_mfma(
    const unsigned char* __restrict__ img, const float* __restrict__ scales,
    const float* __restrict__ bias, const unsigned char* __restrict__ codes,
    float* __restrict__ out) {
  __shared__ __align__(16) unsigned int Tb[16384];   // 64 KiB: [pair32][h2][col64][16B]

  const int t = threadIdx.x;
  const int wid = t >> 6, lane = t & 63, lrow = lane & 31, h = lane >> 5;
  const int g16 = blockIdx.x;
  const int n0 = blockIdx.y * 1024;
  const unsigned char* img_g = img + (size_t)g16 * 65536;

  // stage 64 KiB linearly: 64 segs of 1024 B; wave stages 4 (image == LDS layout)
  #pragma unroll
  for (int i = 0; i < 4; ++i) {
    int gs = wid * 4 + i;
    gld16(img_g + gs * 1024 + lane * 16, (char*)Tb + gs * 1024);
  }

  const char* tb = (const char*)Tb;
  const float sc0 = scales[g16 * 64 + lrow],      bb0 = bias[g16 * 64 + lrow];
  const float sc1 = scales[g16 * 64 + 32 + lrow], bb1 = bias[g16 * 64 + 32 + lrow];

  __syncthreads();                                  // the ONLY barrier

  #pragma unroll
  for (int rt = 0; rt < 2; ++rt) {                  // row-phase split
    const unsigned char* crow =
        codes + (size_t)(n0 + wid * 64 + rt * 32 + lrow) * CBN;

    i32x16 acc[2];
    #pragma unroll
    for (int ct = 0; ct < 2; ++ct)
      #pragma unroll
      for (int e = 0; e < 16; ++e) acc[ct][e] = 0;

    const int gg0 = wid & 7;
    unsigned long long qA = *(const unsigned long long*)(crow + gg0 * 8);

    #pragma unroll
    for (int g = 0; g < 8; ++g) {                   // 8 u64 code groups
      const int gcur = (wid + g) & 7;
      const unsigned long long q = qA;
      if (g < 7) {                                  // prefetch next codes
        const int ggn = (wid + g + 1) & 7;
        qA = *(const unsigned long long*)(crow + ggn * 8);
      }
      #pragma unroll
      for (int pp = 0; pp < 4; ++pp) {              // 4 pairs per group
        const int p = gcur * 4 + pp;                // codebooks 2p (h=0), 2p+1 (h=1)
        const char* pb = tb + p * 2048 + h * 1024 + lrow * 16;
        const i32x4 b0 = *(const i32x4*)pb;         // cols  0..31 (linear, no conflicts)
        const i32x4 b1 = *(const i32x4*)(pb + 512); // cols 32..63
        const unsigned c4 = (unsigned)(q >> ((pp * 2 + h) * 8)) & 15u;
        const unsigned long long tt = 1ULL << ((c4 & 7u) * 8u);
        union { unsigned long long q[2]; i32x4 v; } A;
        A.q[0] = (c4 < 8u) ? tt : 0ULL;
        A.q[1] = (c4 < 8u) ? 0ULL : tt;
        acc[0] = __builtin_amdgcn_mfma_i32_32x32x32_i8(A.v, b0, acc[0], 0, 0, 0);
        acc[1] = __builtin_amdgcn_mfma_i32_32x32x32_i8(A.v, b1, acc[1], 0, 0, 0);
      }
    }

    // write THIS row-phase now (phase A's burst drains under phase B compute).
    // D layout col=lane&31, row=(reg&3)+8*(reg>>2)+4*(lane>>5); each row gets
    // one contiguous 256B store pair (ct=0:+0..31, ct=1:+32..63) per block.
    #pragma unroll
    for (int r = 0; r < 16; ++r) {
      int row = n0 + wid * 64 + rt * 32 + (r & 3) + 8 * (r >> 2) + 4 * h;
      float* orow = out + (size_t)row * DOUTN + g16 * 64 + lrow;
      orow[0]  = fmaf((float)acc[0][r], sc0, bb0);
      orow[32] = fmaf((float)acc[1][r], sc1, bb1);
    }
  }
}

extern "C" void kernel_launch(void* const* d_in, const int* in_sizes, int n_in,
                              void* d_out, int out_size, void* d_ws, size_t ws_size,
                              hipStream_t stream) {
  const float* x    = (const float*)d_in[0];
  const int*   sidx = (const int*)d_in[1];
  const float* sval = (const float*)d_in[2];
  const float* Tg   = (const float*)d_in[3];
  const float* bias = (const float*)d_in[4];
  float* out = (float*)d_out;
  unsigned char* codes  = (unsigned char*)d_ws;                      // 1 MiB
  unsigned char* img    = (unsigned char*)d_ws + (1 << 20);          // 1 MiB
  float*         scales = (float*)((char*)d_ws + (2 << 20));         // 4 KiB

  prep_k<<<64 + NN / 8, 256, 0, stream>>>(x, sidx, sval, Tg, codes, img, scales);
  maddness_mfma<<<dim3(16, 16), 1024, 0, stream>>>(img, scales, bias, codes, out);
}